// Round 1
// baseline (141.471 us; speedup 1.0000x reference)
//
#include <hip/hip_runtime.h>
#include <cmath>

#define B_TOTAL 131072
#define D_IN 64
#define NMOD 64
#define HID 12
#define TPB 128

// ---------------------------------------------------------------------------
// Kernel 1: compute top-2 routing indices from the tiny emb tensors.
// route layout (ints): [0..63]=i1_l0, [64..127]=i2_l0,
//                      [128..191]=i1_l1, [192..255]=i2_l1, [256]=io1, [257]=io2
// emb layout: [T=1, D, M] -> element (d, m) at d*M + m. top-2 over d per m.
// jax.lax.top_k tie-break = lowest index first -> strict '>' keeps first hit.
// ---------------------------------------------------------------------------
__global__ void routing_kernel(const float* __restrict__ emb0,
                               const float* __restrict__ emb1,
                               const float* __restrict__ emb_out,
                               int* __restrict__ route) {
    int t = threadIdx.x;
    const float* e; int m, M, base;
    if (t < 64)        { e = emb0;    m = t;      M = 64; base = 0;   }
    else if (t < 128)  { e = emb1;    m = t - 64; M = 64; base = 128; }
    else if (t == 128) { e = emb_out; m = 0;      M = 1;  base = 256; }
    else return;

    int i1 = 0; float v1 = -INFINITY;
    for (int d = 0; d < 64; ++d) {
        float v = e[d * M + m];
        if (v > v1) { v1 = v; i1 = d; }
    }
    int i2 = 0; float v2 = -INFINITY;
    for (int d = 0; d < 64; ++d) {
        if (d == i1) continue;
        float v = e[d * M + m];
        if (v > v2) { v2 = v; i2 = d; }
    }
    if (t == 128) { route[256] = i1; route[257] = i2; }
    else          { route[base + m] = i1; route[base + 64 + m] = i2; }
}

// ---------------------------------------------------------------------------
// Kernel 2: main fused pipeline. One thread per row.
// Row is staged TRANSPOSED in LDS: xb[feature][thread]. Gather address
// = i*TPB + t, so LDS bank = t % 32 -> conflict-free with no padding, and
// the two 64x128 f32 buffers total exactly 64 KiB.
// Weights + routing indices are wave-uniform -> scalar (s_load) path.
// ---------------------------------------------------------------------------
__global__ __launch_bounds__(TPB) void moe_main(
    const float* __restrict__ x,
    const float* __restrict__ W1_0, const float* __restrict__ b1_0,
    const float* __restrict__ W2_0, const float* __restrict__ b2_0,
    const float* __restrict__ W1_1, const float* __restrict__ b1_1,
    const float* __restrict__ W2_1, const float* __restrict__ b2_1,
    const int* __restrict__ route,
    float* __restrict__ out) {

    __shared__ float xb[D_IN][TPB];   // 32 KiB
    __shared__ float yb[NMOD][TPB];   // 32 KiB

    const int t = threadIdx.x;
    const int b = blockIdx.x * TPB + t;

    // ---- stage this thread's row into its private LDS column ----
    const float4* xr = reinterpret_cast<const float4*>(x + (size_t)b * D_IN);
#pragma unroll
    for (int k = 0; k < D_IN / 4; ++k) {
        float4 v = xr[k];
        xb[4 * k + 0][t] = v.x;
        xb[4 * k + 1][t] = v.y;
        xb[4 * k + 2][t] = v.z;
        xb[4 * k + 3][t] = v.w;
    }
    // no barrier: column t is private to thread t

    // ---- layer 0 ----
#pragma unroll 8
    for (int m = 0; m < NMOD; ++m) {
        const int i1 = route[m];
        const int i2 = route[64 + m];
        const float v1 = xb[i1][t];
        const float v2 = xb[i2][t];
        float acc = b2_0[m];
#pragma unroll
        for (int j = 0; j < HID; ++j) {
            float h = fmaf(v1, W1_0[m * 2 * HID + j],
                     fmaf(v2, W1_0[m * 2 * HID + HID + j], b1_0[m * HID + j]));
            h = fmaxf(h, 0.0f);
            acc = fmaf(h, W2_0[m * HID + j], acc);
        }
        yb[m][t] = acc;
    }

    // ---- layer 1 + final top-2 select ----
    const int io1 = route[256];
    const int io2 = route[257];
    float o1 = 0.0f, o2 = 0.0f;
#pragma unroll 8
    for (int m = 0; m < NMOD; ++m) {
        const int i1 = route[128 + m];
        const int i2 = route[192 + m];
        const float v1 = yb[i1][t];
        const float v2 = yb[i2][t];
        float acc = b2_1[m];
#pragma unroll
        for (int j = 0; j < HID; ++j) {
            float h = fmaf(v1, W1_1[m * 2 * HID + j],
                     fmaf(v2, W1_1[m * 2 * HID + HID + j], b1_1[m * HID + j]));
            h = fmaxf(h, 0.0f);
            acc = fmaf(h, W2_1[m * HID + j], acc);
        }
        o1 = (m == io1) ? acc : o1;
        o2 = (m == io2) ? acc : o2;
    }

    float2 res;
    res.x = 1.0f / (1.0f + __expf(-o1));
    res.y = 1.0f / (1.0f + __expf(-o2));
    reinterpret_cast<float2*>(out)[b] = res;
}

extern "C" void kernel_launch(void* const* d_in, const int* in_sizes, int n_in,
                              void* d_out, int out_size, void* d_ws, size_t ws_size,
                              hipStream_t stream) {
    const float* x       = (const float*)d_in[0];
    // d_in[1] = task_id; NUM_TASKS == 1 so it is always 0 -> emb[0] offset.
    const float* emb0    = (const float*)d_in[2];
    const float* emb1    = (const float*)d_in[3];
    const float* emb_out = (const float*)d_in[4];
    const float* W1_0    = (const float*)d_in[5];
    const float* b1_0    = (const float*)d_in[6];
    const float* W2_0    = (const float*)d_in[7];
    const float* b2_0    = (const float*)d_in[8];
    const float* W1_1    = (const float*)d_in[9];
    const float* b1_1    = (const float*)d_in[10];
    const float* W2_1    = (const float*)d_in[11];
    const float* b2_1    = (const float*)d_in[12];

    int* route = (int*)d_ws;  // 258 ints of scratch

    routing_kernel<<<1, 192, 0, stream>>>(emb0, emb1, emb_out, route);
    moe_main<<<B_TOTAL / TPB, TPB, 0, stream>>>(
        x, W1_0, b1_0, W2_0, b2_0, W1_1, b1_1, W2_1, b2_1,
        route, (float*)d_out);
}

// Round 2
// 45.600 us; speedup vs baseline: 3.1024x; 3.1024x over previous
//
#include <hip/hip_runtime.h>
#include <cmath>

#define NROWS 131072
#define D_IN 64
#define NMOD 64
#define HID 12
#define TPB 256
#define ROWS_PER_WAVE 64
// total waves = NROWS / ROWS_PER_WAVE = 2048 ; blocks = 2048/4 = 512

// ---------------------------------------------------------------------------
// Kernel 1: top-2 routing indices from the tiny emb tensors (unchanged).
// route: [0..63]=i1_l0, [64..127]=i2_l0, [128..191]=i1_l1, [192..255]=i2_l1,
//        [256]=io1, [257]=io2
// ---------------------------------------------------------------------------
__global__ void routing_kernel(const float* __restrict__ emb0,
                               const float* __restrict__ emb1,
                               const float* __restrict__ emb_out,
                               int* __restrict__ route) {
    int t = threadIdx.x;
    const float* e; int m, M, base;
    if (t < 64)        { e = emb0;    m = t;      M = 64; base = 0;   }
    else if (t < 128)  { e = emb1;    m = t - 64; M = 64; base = 128; }
    else if (t == 128) { e = emb_out; m = 0;      M = 1;  base = 256; }
    else return;

    int i1 = 0; float v1 = -INFINITY;
    for (int d = 0; d < 64; ++d) {
        float v = e[d * M + m];
        if (v > v1) { v1 = v; i1 = d; }
    }
    int i2 = 0; float v2 = -INFINITY;
    for (int d = 0; d < 64; ++d) {
        if (d == i1) continue;
        float v = e[d * M + m];
        if (v > v2) { v2 = v; i2 = d; }
    }
    if (t == 128) { route[256] = i1; route[257] = i2; }
    else          { route[base + m] = i1; route[base + 64 + m] = i2; }
}

// ---------------------------------------------------------------------------
// Kernel 2: lane = module. Zero LDS. Each wave owns 64 consecutive rows.
// Per row: coalesced dword load of x[row][lane]; feature gather = 1 bpermute
// (__shfl with per-lane index); per-lane register-resident MLP weights;
// layer-1 gather = shfl of layer-0 outputs (y[m] lives in lane m).
// Outputs collected into one VGPR across 32-row batches -> coalesced store.
// ---------------------------------------------------------------------------
__global__ __launch_bounds__(TPB) void moe_main(
    const float* __restrict__ x,
    const float* __restrict__ W1_0, const float* __restrict__ b1_0,
    const float* __restrict__ W2_0, const float* __restrict__ b2_0,
    const float* __restrict__ W1_1, const float* __restrict__ b1_1,
    const float* __restrict__ W2_1, const float* __restrict__ b2_1,
    const int* __restrict__ route,
    float* __restrict__ out) {

    const int lane = threadIdx.x & 63;
    const int wave = blockIdx.x * (TPB / 64) + (threadIdx.x >> 6);
    const int row0 = wave * ROWS_PER_WAVE;
    const int m = lane;

    // per-lane routing indices (shfl source lanes)
    const int i1_0 = route[m];
    const int i2_0 = route[64 + m];
    const int i1_1 = route[128 + m];
    const int i2_1 = route[192 + m];
    const int io1  = route[256];
    const int io2  = route[257];

    // per-lane (= per-module) weights, fully register-resident
    float w1a0[HID], w1b0[HID], b10[HID], w20[HID];
    float w1a1[HID], w1b1[HID], b11[HID], w21[HID];
#pragma unroll
    for (int j = 0; j < HID; ++j) {
        w1a0[j] = W1_0[m * 2 * HID + j];
        w1b0[j] = W1_0[m * 2 * HID + HID + j];
        b10[j]  = b1_0[m * HID + j];
        w20[j]  = W2_0[m * HID + j];
        w1a1[j] = W1_1[m * 2 * HID + j];
        w1b1[j] = W1_1[m * 2 * HID + HID + j];
        b11[j]  = b1_1[m * HID + j];
        w21[j]  = W2_1[m * HID + j];
    }
    const float b20 = b2_0[m];
    const float b21 = b2_1[m];

    // 2-deep x prefetch (clamped addresses: no OOB, no divergence)
    float xcur = x[(size_t)row0 * D_IN + lane];
    float xnxt = x[(size_t)(row0 + 1) * D_IN + lane];

    float vout = 0.0f;

#pragma unroll 2
    for (int r = 0; r < ROWS_PER_WAVE; ++r) {
        int rpf = row0 + r + 2;
        rpf = rpf < NROWS ? rpf : NROWS - 1;
        const float xpf = x[(size_t)rpf * D_IN + lane];

        // layer 0
        const float v1 = __shfl(xcur, i1_0);
        const float v2 = __shfl(xcur, i2_0);
        float acc = b20;
#pragma unroll
        for (int j = 0; j < HID; ++j) {
            float h = fmaf(v1, w1a0[j], fmaf(v2, w1b0[j], b10[j]));
            h = fmaxf(h, 0.0f);
            acc = fmaf(h, w20[j], acc);
        }

        // layer 1 (gather layer-0 outputs across lanes)
        const float g1 = __shfl(acc, i1_1);
        const float g2 = __shfl(acc, i2_1);
        float acc2 = b21;
#pragma unroll
        for (int j = 0; j < HID; ++j) {
            float h = fmaf(g1, w1a1[j], fmaf(g2, w1b1[j], b11[j]));
            h = fmaxf(h, 0.0f);
            acc2 = fmaf(h, w21[j], acc2);
        }

        // final top-2 select; pack into vout at lanes 2q, 2q+1
        const float o1 = __shfl(acc2, io1);
        const float o2 = __shfl(acc2, io2);
        const int q = r & 31;
        vout = (lane == 2 * q)     ? o1 : vout;
        vout = (lane == 2 * q + 1) ? o2 : vout;

        if ((r & 31) == 31) {
            // sigmoid + coalesced 32-row store
            const float s = 1.0f / (1.0f + __expf(-vout));
            out[(size_t)(row0 + r - 31) * 2 + lane] = s;
        }

        xcur = xnxt;
        xnxt = xpf;
    }
}

extern "C" void kernel_launch(void* const* d_in, const int* in_sizes, int n_in,
                              void* d_out, int out_size, void* d_ws, size_t ws_size,
                              hipStream_t stream) {
    const float* x       = (const float*)d_in[0];
    // d_in[1] = task_id; NUM_TASKS == 1 so always 0.
    const float* emb0    = (const float*)d_in[2];
    const float* emb1    = (const float*)d_in[3];
    const float* emb_out = (const float*)d_in[4];
    const float* W1_0    = (const float*)d_in[5];
    const float* b1_0    = (const float*)d_in[6];
    const float* W2_0    = (const float*)d_in[7];
    const float* b2_0    = (const float*)d_in[8];
    const float* W1_1    = (const float*)d_in[9];
    const float* b1_1    = (const float*)d_in[10];
    const float* W2_1    = (const float*)d_in[11];
    const float* b2_1    = (const float*)d_in[12];

    int* route = (int*)d_ws;  // 258 ints of scratch

    routing_kernel<<<1, 192, 0, stream>>>(emb0, emb1, emb_out, route);

    const int waves = NROWS / ROWS_PER_WAVE;       // 2048
    const int blocks = waves / (TPB / 64);         // 512
    moe_main<<<blocks, TPB, 0, stream>>>(
        x, W1_0, b1_0, W2_0, b2_0, W1_1, b1_1, W2_1, b2_1,
        route, (float*)d_out);
}

// Round 3
// 43.826 us; speedup vs baseline: 3.2280x; 1.0405x over previous
//
#include <hip/hip_runtime.h>
#include <cmath>

#define NROWS 131072
#define D_IN 64
#define NMOD 64
#define HID 12
#define TPB 256
#define ROWS_PER_WAVE 16
// waves = NROWS/ROWS_PER_WAVE = 8192 -> 4 waves/SIMD machine-wide at 128 VGPR

// ---------------------------------------------------------------------------
// Kernel 1: top-2 routing indices from the tiny emb tensors.
// route: [0..63]=i1_l0, [64..127]=i2_l0, [128..191]=i1_l1, [192..255]=i2_l1,
//        [256]=io1, [257]=io2
// ---------------------------------------------------------------------------
__global__ void routing_kernel(const float* __restrict__ emb0,
                               const float* __restrict__ emb1,
                               const float* __restrict__ emb_out,
                               int* __restrict__ route) {
    int t = threadIdx.x;
    const float* e; int m, M, base;
    if (t < 64)        { e = emb0;    m = t;      M = 64; base = 0;   }
    else if (t < 128)  { e = emb1;    m = t - 64; M = 64; base = 128; }
    else if (t == 128) { e = emb_out; m = 0;      M = 1;  base = 256; }
    else return;

    int i1 = 0; float v1 = -INFINITY;
    for (int d = 0; d < 64; ++d) {
        float v = e[d * M + m];
        if (v > v1) { v1 = v; i1 = d; }
    }
    int i2 = 0; float v2 = -INFINITY;
    for (int d = 0; d < 64; ++d) {
        if (d == i1) continue;
        float v = e[d * M + m];
        if (v > v2) { v2 = v; i2 = d; }
    }
    if (t == 128) { route[256] = i1; route[257] = i2; }
    else          { route[base + m] = i1; route[base + 64 + m] = i2; }
}

// ---------------------------------------------------------------------------
// Kernel 2: lane = module, zero LDS, weights register-resident.
// __launch_bounds__(256,4): min 4 waves/EU -> VGPR cap 128, which fits the
// 98 weight floats + working set, so the compiler hoists weight loads out of
// the row loop (at the R1 default cap of 64 it rematerialized them per row).
// 16 rows/wave -> 8192 waves -> exactly 4 waves/SIMD resident (full tier).
// ---------------------------------------------------------------------------
__global__ __launch_bounds__(TPB, 4) void moe_main(
    const float* __restrict__ x,
    const float* __restrict__ W1_0, const float* __restrict__ b1_0,
    const float* __restrict__ W2_0, const float* __restrict__ b2_0,
    const float* __restrict__ W1_1, const float* __restrict__ b1_1,
    const float* __restrict__ W2_1, const float* __restrict__ b2_1,
    const int* __restrict__ route,
    float* __restrict__ out) {

    const int lane = threadIdx.x & 63;
    const int wave = blockIdx.x * (TPB / 64) + (threadIdx.x >> 6);
    const int row0 = wave * ROWS_PER_WAVE;
    const int m = lane;

    // per-lane routing indices (bpermute sources)
    const int i1_0 = route[m];
    const int i2_0 = route[64 + m];
    const int i1_1 = route[128 + m];
    const int i2_1 = route[192 + m];
    // uniform final indices -> force SGPR so the gather is v_readlane
    const int io1 = __builtin_amdgcn_readfirstlane(route[256]);
    const int io2 = __builtin_amdgcn_readfirstlane(route[257]);

    // per-lane (= per-module) weights, register-resident
    float w1a0[HID], w1b0[HID], b10[HID], w20[HID];
    float w1a1[HID], w1b1[HID], b11[HID], w21[HID];
#pragma unroll
    for (int j = 0; j < HID; ++j) {
        w1a0[j] = W1_0[m * 2 * HID + j];
        w1b0[j] = W1_0[m * 2 * HID + HID + j];
        b10[j]  = b1_0[m * HID + j];
        w20[j]  = W2_0[m * HID + j];
        w1a1[j] = W1_1[m * 2 * HID + j];
        w1b1[j] = W1_1[m * 2 * HID + HID + j];
        b11[j]  = b1_1[m * HID + j];
        w21[j]  = W2_1[m * HID + j];
    }
    const float b20 = b2_0[m];
    const float b21 = b2_1[m];

    float xcur = x[(size_t)row0 * D_IN + lane];
    float vout = 0.0f;

#pragma unroll 2
    for (int r = 0; r < ROWS_PER_WAVE; ++r) {
        int rn = row0 + r + 1;
        rn = rn < NROWS ? rn : NROWS - 1;
        const float xnxt = x[(size_t)rn * D_IN + lane];

        // layer 0
        const float v1 = __shfl(xcur, i1_0);
        const float v2 = __shfl(xcur, i2_0);
        float acc = b20;
#pragma unroll
        for (int j = 0; j < HID; ++j) {
            float h = fmaf(v1, w1a0[j], fmaf(v2, w1b0[j], b10[j]));
            h = fmaxf(h, 0.0f);
            acc = fmaf(h, w20[j], acc);
        }

        // layer 1
        const float g1 = __shfl(acc, i1_1);
        const float g2 = __shfl(acc, i2_1);
        float acc2 = b21;
#pragma unroll
        for (int j = 0; j < HID; ++j) {
            float h = fmaf(g1, w1a1[j], fmaf(g2, w1b1[j], b11[j]));
            h = fmaxf(h, 0.0f);
            acc2 = fmaf(h, w21[j], acc2);
        }

        // final top-2: uniform lanes -> v_readlane (SGPR), then lane-select
        const float o1 = __int_as_float(
            __builtin_amdgcn_readlane(__float_as_int(acc2), io1));
        const float o2 = __int_as_float(
            __builtin_amdgcn_readlane(__float_as_int(acc2), io2));
        vout = (lane == 2 * r)     ? o1 : vout;
        vout = (lane == 2 * r + 1) ? o2 : vout;

        xcur = xnxt;
    }

    // sigmoid + one coalesced 128B store per wave (lanes 0..31 = 16 rows x 2)
    if (lane < 2 * ROWS_PER_WAVE) {
        const float s = 1.0f / (1.0f + __expf(-vout));
        out[(size_t)row0 * 2 + lane] = s;
    }
}

extern "C" void kernel_launch(void* const* d_in, const int* in_sizes, int n_in,
                              void* d_out, int out_size, void* d_ws, size_t ws_size,
                              hipStream_t stream) {
    const float* x       = (const float*)d_in[0];
    // d_in[1] = task_id; NUM_TASKS == 1 so always 0.
    const float* emb0    = (const float*)d_in[2];
    const float* emb1    = (const float*)d_in[3];
    const float* emb_out = (const float*)d_in[4];
    const float* W1_0    = (const float*)d_in[5];
    const float* b1_0    = (const float*)d_in[6];
    const float* W2_0    = (const float*)d_in[7];
    const float* b2_0    = (const float*)d_in[8];
    const float* W1_1    = (const float*)d_in[9];
    const float* b1_1    = (const float*)d_in[10];
    const float* W2_1    = (const float*)d_in[11];
    const float* b2_1    = (const float*)d_in[12];

    int* route = (int*)d_ws;  // 258 ints of scratch

    routing_kernel<<<1, 192, 0, stream>>>(emb0, emb1, emb_out, route);

    const int waves = NROWS / ROWS_PER_WAVE;       // 8192
    const int blocks = waves / (TPB / 64);         // 2048
    moe_main<<<blocks, TPB, 0, stream>>>(
        x, W1_0, b1_0, W2_0, b2_0, W1_1, b1_1, W2_1, b2_1,
        route, (float*)d_out);
}

// Round 4
// 36.966 us; speedup vs baseline: 3.8270x; 1.1855x over previous
//
#include <hip/hip_runtime.h>
#include <cmath>

#define NROWS 131072
#define D_IN 64
#define NMOD 64
#define HID 12
#define TPB 256
#define RPW 16
// waves = NROWS/RPW = 8192 -> 4 waves/SIMD at <=128 VGPR

// ---------------------------------------------------------------------------
// Kernel 1: top-2 routing indices from the tiny emb tensors.
// route: [0..63]=i1_l0, [64..127]=i2_l0, [128..191]=i1_l1, [192..255]=i2_l1,
//        [256]=io1, [257]=io2
// ---------------------------------------------------------------------------
__global__ void routing_kernel(const float* __restrict__ emb0,
                               const float* __restrict__ emb1,
                               const float* __restrict__ emb_out,
                               int* __restrict__ route) {
    int t = threadIdx.x;
    const float* e; int m, M, base;
    if (t < 64)        { e = emb0;    m = t;      M = 64; base = 0;   }
    else if (t < 128)  { e = emb1;    m = t - 64; M = 64; base = 128; }
    else if (t == 128) { e = emb_out; m = 0;      M = 1;  base = 256; }
    else return;

    int i1 = 0; float v1 = -INFINITY;
    for (int d = 0; d < 64; ++d) {
        float v = e[d * M + m];
        if (v > v1) { v1 = v; i1 = d; }
    }
    int i2 = 0; float v2 = -INFINITY;
    for (int d = 0; d < 64; ++d) {
        if (d == i1) continue;
        float v = e[d * M + m];
        if (v > v2) { v2 = v; i2 = d; }
    }
    if (t == 128) { route[256] = i1; route[257] = i2; }
    else          { route[base + m] = i1; route[base + 64 + m] = i2; }
}

// ---------------------------------------------------------------------------
// Kernel 2: lane = module, zero LDS, PHASE-SPLIT so layer-0 and layer-1
// weight sets are never live at the same time (49 regs each instead of 98
// together). Each wave owns 16 rows; each phase is a fully-unrolled sweep
// over 16 independent rows -> deep ILP, split accumulators halve the
// dependent-FMA chain. y[r] (layer-0 outputs, lane = module) carries the
// inter-layer state in 16 VGPRs; layer-1 feature gather is one bpermute.
// ---------------------------------------------------------------------------
__global__ __launch_bounds__(TPB, 4) void moe_main(
    const float* __restrict__ x,
    const float* __restrict__ W1_0, const float* __restrict__ b1_0,
    const float* __restrict__ W2_0, const float* __restrict__ b2_0,
    const float* __restrict__ W1_1, const float* __restrict__ b1_1,
    const float* __restrict__ W2_1, const float* __restrict__ b2_1,
    const int* __restrict__ route,
    float* __restrict__ out) {

    const int lane = threadIdx.x & 63;
    const int wave = blockIdx.x * (TPB / 64) + (threadIdx.x >> 6);
    const int row0 = wave * RPW;
    const int m = lane;

    // routing (bpermute source lanes); final pair uniform -> SGPR readlane idx
    const int i1_0 = route[m];
    const int i2_0 = route[64 + m];
    const int i1_1 = route[128 + m];
    const int i2_1 = route[192 + m];
    const int io1 = __builtin_amdgcn_readfirstlane(route[256]);
    const int io2 = __builtin_amdgcn_readfirstlane(route[257]);

    // ---- all 16 x values up front (coalesced dword loads, 16 in flight) ----
    float xv[RPW];
#pragma unroll
    for (int r = 0; r < RPW; ++r)
        xv[r] = x[(size_t)(row0 + r) * D_IN + lane];

    // =====================  PHASE A : layer 0  =====================
    float w1a0[HID], w1b0[HID], b10[HID], w20[HID];
    {
        const float4* W1p = reinterpret_cast<const float4*>(W1_0 + m * 2 * HID);
        const float4* b1p = reinterpret_cast<const float4*>(b1_0 + m * HID);
        const float4* W2p = reinterpret_cast<const float4*>(W2_0 + m * HID);
#pragma unroll
        for (int q = 0; q < 3; ++q) {
            float4 a = W1p[q], b = W1p[3 + q], c = b1p[q], d = W2p[q];
            w1a0[4*q] = a.x; w1a0[4*q+1] = a.y; w1a0[4*q+2] = a.z; w1a0[4*q+3] = a.w;
            w1b0[4*q] = b.x; w1b0[4*q+1] = b.y; w1b0[4*q+2] = b.z; w1b0[4*q+3] = b.w;
            b10[4*q]  = c.x; b10[4*q+1]  = c.y; b10[4*q+2]  = c.z; b10[4*q+3]  = c.w;
            w20[4*q]  = d.x; w20[4*q+1]  = d.y; w20[4*q+2]  = d.z; w20[4*q+3]  = d.w;
        }
    }
    const float b20 = b2_0[m];

    float y[RPW];
#pragma unroll
    for (int r = 0; r < RPW; ++r) {
        const float v1 = __shfl(xv[r], i1_0);
        const float v2 = __shfl(xv[r], i2_0);
        float a0 = b20, a1 = 0.0f;
#pragma unroll
        for (int j = 0; j < HID / 2; ++j) {
            float h = fmaf(v1, w1a0[j], fmaf(v2, w1b0[j], b10[j]));
            a0 = fmaf(fmaxf(h, 0.0f), w20[j], a0);
        }
#pragma unroll
        for (int j = HID / 2; j < HID; ++j) {
            float h = fmaf(v1, w1a0[j], fmaf(v2, w1b0[j], b10[j]));
            a1 = fmaf(fmaxf(h, 0.0f), w20[j], a1);
        }
        y[r] = a0 + a1;
    }

    __builtin_amdgcn_sched_barrier(0);  // keep phase-A regs dead before B

    // =====================  PHASE B : layer 1  =====================
    float w1a1[HID], w1b1[HID], b11[HID], w21[HID];
    {
        const float4* W1p = reinterpret_cast<const float4*>(W1_1 + m * 2 * HID);
        const float4* b1p = reinterpret_cast<const float4*>(b1_1 + m * HID);
        const float4* W2p = reinterpret_cast<const float4*>(W2_1 + m * HID);
#pragma unroll
        for (int q = 0; q < 3; ++q) {
            float4 a = W1p[q], b = W1p[3 + q], c = b1p[q], d = W2p[q];
            w1a1[4*q] = a.x; w1a1[4*q+1] = a.y; w1a1[4*q+2] = a.z; w1a1[4*q+3] = a.w;
            w1b1[4*q] = b.x; w1b1[4*q+1] = b.y; w1b1[4*q+2] = b.z; w1b1[4*q+3] = b.w;
            b11[4*q]  = c.x; b11[4*q+1]  = c.y; b11[4*q+2]  = c.z; b11[4*q+3]  = c.w;
            w21[4*q]  = d.x; w21[4*q+1]  = d.y; w21[4*q+2]  = d.z; w21[4*q+3]  = d.w;
        }
    }
    const float b21 = b2_1[m];

    float vout = 0.0f;
#pragma unroll
    for (int r = 0; r < RPW; ++r) {
        const float g1 = __shfl(y[r], i1_1);
        const float g2 = __shfl(y[r], i2_1);
        float a0 = b21, a1 = 0.0f;
#pragma unroll
        for (int j = 0; j < HID / 2; ++j) {
            float h = fmaf(g1, w1a1[j], fmaf(g2, w1b1[j], b11[j]));
            a0 = fmaf(fmaxf(h, 0.0f), w21[j], a0);
        }
#pragma unroll
        for (int j = HID / 2; j < HID; ++j) {
            float h = fmaf(g1, w1a1[j], fmaf(g2, w1b1[j], b11[j]));
            a1 = fmaf(fmaxf(h, 0.0f), w21[j], a1);
        }
        const float acc2 = a0 + a1;

        const float o1 = __int_as_float(
            __builtin_amdgcn_readlane(__float_as_int(acc2), io1));
        const float o2 = __int_as_float(
            __builtin_amdgcn_readlane(__float_as_int(acc2), io2));
        vout = (lane == 2 * r)     ? o1 : vout;
        vout = (lane == 2 * r + 1) ? o2 : vout;
    }

    // sigmoid + one coalesced 128B store per wave (lanes 0..31 = 16 rows x 2)
    if (lane < 2 * RPW) {
        const float s = 1.0f / (1.0f + __expf(-vout));
        out[(size_t)row0 * 2 + lane] = s;
    }
}

extern "C" void kernel_launch(void* const* d_in, const int* in_sizes, int n_in,
                              void* d_out, int out_size, void* d_ws, size_t ws_size,
                              hipStream_t stream) {
    const float* x       = (const float*)d_in[0];
    // d_in[1] = task_id; NUM_TASKS == 1 so always 0.
    const float* emb0    = (const float*)d_in[2];
    const float* emb1    = (const float*)d_in[3];
    const float* emb_out = (const float*)d_in[4];
    const float* W1_0    = (const float*)d_in[5];
    const float* b1_0    = (const float*)d_in[6];
    const float* W2_0    = (const float*)d_in[7];
    const float* b2_0    = (const float*)d_in[8];
    const float* W1_1    = (const float*)d_in[9];
    const float* b1_1    = (const float*)d_in[10];
    const float* W2_1    = (const float*)d_in[11];
    const float* b2_1    = (const float*)d_in[12];

    int* route = (int*)d_ws;  // 258 ints of scratch

    routing_kernel<<<1, 192, 0, stream>>>(emb0, emb1, emb_out, route);

    const int waves = NROWS / RPW;                 // 8192
    const int blocks = waves / (TPB / 64);         // 2048
    moe_main<<<blocks, TPB, 0, stream>>>(
        x, W1_0, b1_0, W2_0, b2_0, W1_1, b1_1, W2_1, b2_1,
        route, (float*)d_out);
}

// Round 6
// 36.417 us; speedup vs baseline: 3.8847x; 1.0151x over previous
//
#include <hip/hip_runtime.h>
#include <cmath>

#define NROWS 131072
#define D_IN 64
#define NMOD 64
#define HID 12
#define TPB 256
#define RPW 16
// waves = NROWS/RPW = 8192 -> 4 waves/SIMD at <=128 VGPR

// NOTE: __builtin_amdgcn_cvt_pkrtz returns __fp16 ext_vector(2); use that
// exact type for all packed-f16 values (R4 failed to compile with _Float16).
typedef __fp16 h2 __attribute__((ext_vector_type(2)));

__device__ __forceinline__ h2 pk_relu(h2 a) {
    asm("v_pk_max_f16 %0, %1, 0" : "=v"(a) : "v"(a));
    return a;
}
__device__ __forceinline__ h2 shfl_h2(h2 v, int src) {
    union { h2 h; int i; } u; u.h = v;
    u.i = __shfl(u.i, src);
    return u.h;
}
__device__ __forceinline__ float rl(float v, int sl) {
    return __int_as_float(__builtin_amdgcn_readlane(__float_as_int(v), sl));
}

// ---------------------------------------------------------------------------
// Kernel 1: top-2 routing indices from the tiny emb tensors.
// route: [0..63]=i1_l0, [64..127]=i2_l0, [128..191]=i1_l1, [192..255]=i2_l1,
//        [256]=io1, [257]=io2
// ---------------------------------------------------------------------------
__global__ void routing_kernel(const float* __restrict__ emb0,
                               const float* __restrict__ emb1,
                               const float* __restrict__ emb_out,
                               int* __restrict__ route) {
    int t = threadIdx.x;
    const float* e; int m, M, base;
    if (t < 64)        { e = emb0;    m = t;      M = 64; base = 0;   }
    else if (t < 128)  { e = emb1;    m = t - 64; M = 64; base = 128; }
    else if (t == 128) { e = emb_out; m = 0;      M = 1;  base = 256; }
    else return;

    int i1 = 0; float v1 = -INFINITY;
    for (int d = 0; d < 64; ++d) {
        float v = e[d * M + m];
        if (v > v1) { v1 = v; i1 = d; }
    }
    int i2 = 0; float v2 = -INFINITY;
    for (int d = 0; d < 64; ++d) {
        if (d == i1) continue;
        float v = e[d * M + m];
        if (v > v2) { v2 = v; i2 = d; }
    }
    if (t == 128) { route[256] = i1; route[257] = i2; }
    else          { route[base + m] = i1; route[base + 64 + m] = i2; }
}

// ---------------------------------------------------------------------------
// Kernel 2: lane = module, zero LDS, phase-split, PACKED-F16 row pairs.
// Rows (2q, 2q+1) share one h2 register: one bpermute gathers the routed
// feature for both rows; hidden layer = v_pk_fma_f16/v_pk_max_f16 (2x f32
// FLOP rate). Layer-0 accumulates in f16 (y err ~4e-3 worst); layer-1
// accumulates in f32 (feeds the output). Weights held as duplicated-f16
// pairs (1 VGPR each) except layer-1 W2 which stays f32.
// ---------------------------------------------------------------------------
__global__ __launch_bounds__(TPB, 4) void moe_main(
    const float* __restrict__ x,
    const float* __restrict__ W1_0, const float* __restrict__ b1_0,
    const float* __restrict__ W2_0, const float* __restrict__ b2_0,
    const float* __restrict__ W1_1, const float* __restrict__ b1_1,
    const float* __restrict__ W2_1, const float* __restrict__ b2_1,
    const int* __restrict__ route,
    float* __restrict__ out) {

    const int lane = threadIdx.x & 63;
    const int wave = blockIdx.x * (TPB / 64) + (threadIdx.x >> 6);
    const int row0 = wave * RPW;
    const int m = lane;

    const int i1_0 = route[m];
    const int i2_0 = route[64 + m];
    const int i1_1 = route[128 + m];
    const int i2_1 = route[192 + m];
    const int io1 = __builtin_amdgcn_readfirstlane(route[256]);
    const int io2 = __builtin_amdgcn_readfirstlane(route[257]);

    // ---- load 16 x values, pack row pairs into f16 (RTZ; eps ~1e-3 rel) ----
    h2 xp[RPW / 2];
#pragma unroll
    for (int q = 0; q < RPW / 2; ++q) {
        const float a = x[(size_t)(row0 + 2 * q)     * D_IN + lane];
        const float b = x[(size_t)(row0 + 2 * q + 1) * D_IN + lane];
        xp[q] = __builtin_amdgcn_cvt_pkrtz(a, b);
    }

    // =====================  PHASE A : layer 0 (all f16)  =====================
    h2 w1a0d[HID], w1b0d[HID], b10d[HID], w20d[HID];
    {
        const float4* W1p = reinterpret_cast<const float4*>(W1_0 + m * 2 * HID);
        const float4* b1p = reinterpret_cast<const float4*>(b1_0 + m * HID);
        const float4* W2p = reinterpret_cast<const float4*>(W2_0 + m * HID);
#pragma unroll
        for (int q = 0; q < 3; ++q) {
            float4 a = W1p[q], b = W1p[3 + q], c = b1p[q], d = W2p[q];
            w1a0d[4*q]   = __builtin_amdgcn_cvt_pkrtz(a.x, a.x);
            w1a0d[4*q+1] = __builtin_amdgcn_cvt_pkrtz(a.y, a.y);
            w1a0d[4*q+2] = __builtin_amdgcn_cvt_pkrtz(a.z, a.z);
            w1a0d[4*q+3] = __builtin_amdgcn_cvt_pkrtz(a.w, a.w);
            w1b0d[4*q]   = __builtin_amdgcn_cvt_pkrtz(b.x, b.x);
            w1b0d[4*q+1] = __builtin_amdgcn_cvt_pkrtz(b.y, b.y);
            w1b0d[4*q+2] = __builtin_amdgcn_cvt_pkrtz(b.z, b.z);
            w1b0d[4*q+3] = __builtin_amdgcn_cvt_pkrtz(b.w, b.w);
            b10d[4*q]    = __builtin_amdgcn_cvt_pkrtz(c.x, c.x);
            b10d[4*q+1]  = __builtin_amdgcn_cvt_pkrtz(c.y, c.y);
            b10d[4*q+2]  = __builtin_amdgcn_cvt_pkrtz(c.z, c.z);
            b10d[4*q+3]  = __builtin_amdgcn_cvt_pkrtz(c.w, c.w);
            w20d[4*q]    = __builtin_amdgcn_cvt_pkrtz(d.x, d.x);
            w20d[4*q+1]  = __builtin_amdgcn_cvt_pkrtz(d.y, d.y);
            w20d[4*q+2]  = __builtin_amdgcn_cvt_pkrtz(d.z, d.z);
            w20d[4*q+3]  = __builtin_amdgcn_cvt_pkrtz(d.w, d.w);
        }
    }
    const float b20f = b2_0[m];
    const h2 b20d = __builtin_amdgcn_cvt_pkrtz(b20f, b20f);

    h2 y[RPW / 2];
#pragma unroll
    for (int q = 0; q < RPW / 2; ++q) {
        const h2 v1 = shfl_h2(xp[q], i1_0);
        const h2 v2 = shfl_h2(xp[q], i2_0);
        h2 a0 = b20d;
        h2 a1 = {(__fp16)0.0f, (__fp16)0.0f};
#pragma unroll
        for (int j = 0; j < HID / 2; ++j) {
            h2 hd = v2 * w1b0d[j] + b10d[j];
            hd = v1 * w1a0d[j] + hd;
            hd = pk_relu(hd);
            a0 = hd * w20d[j] + a0;
        }
#pragma unroll
        for (int j = HID / 2; j < HID; ++j) {
            h2 hd = v2 * w1b0d[j] + b10d[j];
            hd = v1 * w1a0d[j] + hd;
            hd = pk_relu(hd);
            a1 = hd * w20d[j] + a1;
        }
        y[q] = a0 + a1;
    }

    __builtin_amdgcn_sched_barrier(0);  // keep phase-A weight regs dead here

    // ============  PHASE B : layer 1 (f16 hidden, f32 accumulate)  ============
    h2 w1a1d[HID], w1b1d[HID], b11d[HID];
    float w21f[HID];
    {
        const float4* W1p = reinterpret_cast<const float4*>(W1_1 + m * 2 * HID);
        const float4* b1p = reinterpret_cast<const float4*>(b1_1 + m * HID);
        const float4* W2p = reinterpret_cast<const float4*>(W2_1 + m * HID);
#pragma unroll
        for (int q = 0; q < 3; ++q) {
            float4 a = W1p[q], b = W1p[3 + q], c = b1p[q], d = W2p[q];
            w1a1d[4*q]   = __builtin_amdgcn_cvt_pkrtz(a.x, a.x);
            w1a1d[4*q+1] = __builtin_amdgcn_cvt_pkrtz(a.y, a.y);
            w1a1d[4*q+2] = __builtin_amdgcn_cvt_pkrtz(a.z, a.z);
            w1a1d[4*q+3] = __builtin_amdgcn_cvt_pkrtz(a.w, a.w);
            w1b1d[4*q]   = __builtin_amdgcn_cvt_pkrtz(b.x, b.x);
            w1b1d[4*q+1] = __builtin_amdgcn_cvt_pkrtz(b.y, b.y);
            w1b1d[4*q+2] = __builtin_amdgcn_cvt_pkrtz(b.z, b.z);
            w1b1d[4*q+3] = __builtin_amdgcn_cvt_pkrtz(b.w, b.w);
            b11d[4*q]    = __builtin_amdgcn_cvt_pkrtz(c.x, c.x);
            b11d[4*q+1]  = __builtin_amdgcn_cvt_pkrtz(c.y, c.y);
            b11d[4*q+2]  = __builtin_amdgcn_cvt_pkrtz(c.z, c.z);
            b11d[4*q+3]  = __builtin_amdgcn_cvt_pkrtz(c.w, c.w);
            w21f[4*q]   = d.x;
            w21f[4*q+1] = d.y;
            w21f[4*q+2] = d.z;
            w21f[4*q+3] = d.w;
        }
    }
    const float b21 = b2_1[m];

    float vout = 0.0f;
#pragma unroll
    for (int q = 0; q < RPW / 2; ++q) {
        const h2 g1 = shfl_h2(y[q], i1_1);
        const h2 g2 = shfl_h2(y[q], i2_1);
        float alo0 = b21, ahi0 = b21, alo1 = 0.0f, ahi1 = 0.0f;
#pragma unroll
        for (int j = 0; j < HID; ++j) {
            h2 hd = g2 * w1b1d[j] + b11d[j];
            hd = g1 * w1a1d[j] + hd;
            hd = pk_relu(hd);
            const float hlo = (float)hd[0];
            const float hhi = (float)hd[1];
            if (j & 1) {
                alo1 = fmaf(hlo, w21f[j], alo1);
                ahi1 = fmaf(hhi, w21f[j], ahi1);
            } else {
                alo0 = fmaf(hlo, w21f[j], alo0);
                ahi0 = fmaf(hhi, w21f[j], ahi0);
            }
        }
        const float alo = alo0 + alo1;   // row 2q   module output
        const float ahi = ahi0 + ahi1;   // row 2q+1 module output

        // final top-2 (uniform lanes -> readlane), pack into vout
        const float o1lo = rl(alo, io1), o2lo = rl(alo, io2);
        const float o1hi = rl(ahi, io1), o2hi = rl(ahi, io2);
        vout = (lane == 4 * q)     ? o1lo : vout;
        vout = (lane == 4 * q + 1) ? o2lo : vout;
        vout = (lane == 4 * q + 2) ? o1hi : vout;
        vout = (lane == 4 * q + 3) ? o2hi : vout;
    }

    // sigmoid + one coalesced 128B store per wave (lanes 0..31 = 16 rows x 2)
    if (lane < 2 * RPW) {
        const float s = 1.0f / (1.0f + __expf(-vout));
        out[(size_t)row0 * 2 + lane] = s;
    }
}

extern "C" void kernel_launch(void* const* d_in, const int* in_sizes, int n_in,
                              void* d_out, int out_size, void* d_ws, size_t ws_size,
                              hipStream_t stream) {
    const float* x       = (const float*)d_in[0];
    // d_in[1] = task_id; NUM_TASKS == 1 so always 0.
    const float* emb0    = (const float*)d_in[2];
    const float* emb1    = (const float*)d_in[3];
    const float* emb_out = (const float*)d_in[4];
    const float* W1_0    = (const float*)d_in[5];
    const float* b1_0    = (const float*)d_in[6];
    const float* W2_0    = (const float*)d_in[7];
    const float* b2_0    = (const float*)d_in[8];
    const float* W1_1    = (const float*)d_in[9];
    const float* b1_1    = (const float*)d_in[10];
    const float* W2_1    = (const float*)d_in[11];
    const float* b2_1    = (const float*)d_in[12];

    int* route = (int*)d_ws;  // 258 ints of scratch

    routing_kernel<<<1, 192, 0, stream>>>(emb0, emb1, emb_out, route);

    const int waves = NROWS / RPW;                 // 8192
    const int blocks = waves / (TPB / 64);         // 2048
    moe_main<<<blocks, TPB, 0, stream>>>(
        x, W1_0, b1_0, W2_0, b2_0, W1_1, b1_1, W2_1, b2_1,
        route, (float*)d_out);
}